// Round 1
// baseline (197.126 us; speedup 1.0000x reference)
//
#include <hip/hip_runtime.h>

#define DM    1024
#define NTOK  32768   // B*S
#define NRED  16384
#define NSAVE 16384

// ---------------------------------------------------------------------------
// init: zero cnt/need, inv=-1, counter=0
// ---------------------------------------------------------------------------
__global__ __launch_bounds__(256) void init_kernel(int* __restrict__ cnt,
                                                   int* __restrict__ need,
                                                   int* __restrict__ inv,
                                                   int* __restrict__ counter) {
    int t = blockIdx.x * 256 + threadIdx.x;
    if (t < NTOK) { cnt[t] = 0; need[t] = 0; inv[t] = -1; }
    if (t == 0) *counter = 0;
}

// ---------------------------------------------------------------------------
// prep: cnt[red[j]]++ ; mark need[sav[j]-1]
// ---------------------------------------------------------------------------
__global__ __launch_bounds__(256) void prep_kernel(const int* __restrict__ red,
                                                   const int* __restrict__ sav,
                                                   int* __restrict__ cnt,
                                                   int* __restrict__ need) {
    int j = blockIdx.x * 256 + threadIdx.x;
    if (j >= NRED) return;
    atomicAdd(&cnt[red[j]], 1);
    int s = sav[j];
    if (s > 0) need[s - 1] = 1;
}

// ---------------------------------------------------------------------------
// compact: rows that are both reduced and feed a saved neighbor
// ---------------------------------------------------------------------------
__global__ __launch_bounds__(256) void compact_kernel(const int* __restrict__ cnt,
                                                      const int* __restrict__ need,
                                                      int* __restrict__ inv,
                                                      int* __restrict__ list,
                                                      int* __restrict__ counter) {
    int t = blockIdx.x * 256 + threadIdx.x;
    if (t >= NTOK) return;
    if (need[t] && cnt[t] > 0) {
        int pos = atomicAdd(counter, 1);
        inv[t] = pos;
        list[pos] = t;
    }
}

// ---------------------------------------------------------------------------
// GEMM: T[m, n] = sum_k X[list[m], k] * W[n, k]   (fp32, 64x64 tile, BK=32)
// grid = (DM/64, NRED/64); blocks with m0 >= M exit early.
// ---------------------------------------------------------------------------
__global__ __launch_bounds__(256) void gemm_kernel(const float* __restrict__ X,
                                                   const float* __restrict__ W,
                                                   const int* __restrict__ list,
                                                   const int* __restrict__ counter,
                                                   float* __restrict__ T) {
    const int M = *counter;
    const int m0 = blockIdx.y * 64;
    if (m0 >= M) return;
    const int n0 = blockIdx.x * 64;

    __shared__ float As[32][68];   // [k][m], +4 pad
    __shared__ float Bs[32][68];   // [k][n]

    const int tid = threadIdx.x;
    const int tx = tid & 15;          // n quad
    const int ty = tid >> 4;          // m quad
    const int lr = tid >> 2;          // load row 0..63
    const int lk = (tid & 3) * 8;     // load k offset 0/8/16/24

    int am = m0 + lr;
    int src = list[am < M ? am : (M - 1)];
    const float* Arow = X + (size_t)src * DM;
    const float* Brow = W + (size_t)(n0 + lr) * DM;

    float acc[4][4] = {{0.f, 0.f, 0.f, 0.f}, {0.f, 0.f, 0.f, 0.f},
                       {0.f, 0.f, 0.f, 0.f}, {0.f, 0.f, 0.f, 0.f}};

    for (int k0 = 0; k0 < DM; k0 += 32) {
        float4 a0 = *(const float4*)(Arow + k0 + lk);
        float4 a1 = *(const float4*)(Arow + k0 + lk + 4);
        float4 b0 = *(const float4*)(Brow + k0 + lk);
        float4 b1 = *(const float4*)(Brow + k0 + lk + 4);
        __syncthreads();
        As[lk + 0][lr] = a0.x; As[lk + 1][lr] = a0.y;
        As[lk + 2][lr] = a0.z; As[lk + 3][lr] = a0.w;
        As[lk + 4][lr] = a1.x; As[lk + 5][lr] = a1.y;
        As[lk + 6][lr] = a1.z; As[lk + 7][lr] = a1.w;
        Bs[lk + 0][lr] = b0.x; Bs[lk + 1][lr] = b0.y;
        Bs[lk + 2][lr] = b0.z; Bs[lk + 3][lr] = b0.w;
        Bs[lk + 4][lr] = b1.x; Bs[lk + 5][lr] = b1.y;
        Bs[lk + 6][lr] = b1.z; Bs[lk + 7][lr] = b1.w;
        __syncthreads();
        #pragma unroll
        for (int k = 0; k < 32; ++k) {
            float a[4], b[4];
            #pragma unroll
            for (int i = 0; i < 4; ++i) a[i] = As[k][ty * 4 + i];
            #pragma unroll
            for (int j = 0; j < 4; ++j) b[j] = Bs[k][tx * 4 + j];
            #pragma unroll
            for (int i = 0; i < 4; ++i)
                #pragma unroll
                for (int j = 0; j < 4; ++j)
                    acc[i][j] += a[i] * b[j];
        }
    }
    #pragma unroll
    for (int i = 0; i < 4; ++i) {
        int m = m0 + ty * 4 + i;
        if (m < M) {
            float4* trow = (float4*)(T + (size_t)m * DM + n0 + tx * 4);
            *trow = make_float4(acc[i][0], acc[i][1], acc[i][2], acc[i][3]);
        }
    }
}

// ---------------------------------------------------------------------------
// epilogue: out[r] = x[s] + cnt[s-1] * T[inv[s-1]]
// ---------------------------------------------------------------------------
__global__ __launch_bounds__(256) void out_kernel(const float* __restrict__ X,
                                                  const float* __restrict__ T,
                                                  const int* __restrict__ sav,
                                                  const int* __restrict__ cnt,
                                                  const int* __restrict__ inv,
                                                  float* __restrict__ out) {
    int r = blockIdx.x;
    int d = threadIdx.x;                 // float4 lane, 0..255
    int s = sav[r];
    const float4* xr = (const float4*)(X + (size_t)s * DM);
    float4 v = xr[d];
    if (s > 0) {
        int t = s - 1;
        int c = cnt[t];
        if (c > 0) {
            float fc = (float)c;
            const float4* tr = (const float4*)(T + (size_t)inv[t] * DM);
            float4 w = tr[d];
            v.x += fc * w.x; v.y += fc * w.y;
            v.z += fc * w.z; v.w += fc * w.w;
        }
    }
    ((float4*)out)[(size_t)r * (DM / 4) + d] = v;
}

// ---------------------------------------------------------------------------
extern "C" void kernel_launch(void* const* d_in, const int* in_sizes, int n_in,
                              void* d_out, int out_size, void* d_ws, size_t ws_size,
                              hipStream_t stream) {
    const float* X   = (const float*)d_in[0];
    const float* W   = (const float*)d_in[1];
    const int*   sav = (const int*)d_in[2];   // ids_to_save
    const int*   red = (const int*)d_in[3];   // ids_to_reduce
    float* out = (float*)d_out;

    char* ws = (char*)d_ws;
    int* counter = (int*)ws;                  // [0..63] pad
    int* cnt  = (int*)ws + 64;                // 32768
    int* need = cnt + NTOK;                   // 32768
    int* inv  = need + NTOK;                  // 32768
    int* list = inv + NTOK;                   // 16384
    float* T  = (float*)(ws + (1 << 20));     // 16384 x 1024 fp32 = 64 MB

    init_kernel<<<NTOK / 256, 256, 0, stream>>>(cnt, need, inv, counter);
    prep_kernel<<<NRED / 256, 256, 0, stream>>>(red, sav, cnt, need);
    compact_kernel<<<NTOK / 256, 256, 0, stream>>>(cnt, need, inv, list, counter);

    dim3 ggrid(DM / 64, NRED / 64);           // 16 x 256, early-exit on m0 >= M
    gemm_kernel<<<ggrid, 256, 0, stream>>>(X, W, list, counter, T);

    out_kernel<<<NSAVE, 256, 0, stream>>>(X, T, sav, cnt, inv, out);
}

// Round 2
// 76.696 us; speedup vs baseline: 2.5702x; 2.5702x over previous
//
#include <hip/hip_runtime.h>

#define DM    1024
#define NTOK  32768   // B*S
#define NRED  16384
#define NSAVE 16384

typedef __attribute__((ext_vector_type(8))) short bf16x8;
typedef __attribute__((ext_vector_type(4))) float f32x4;

__device__ __forceinline__ ushort f2bf(float f) {
    union { float f; unsigned u; } v; v.f = f;
    unsigned r = (v.u + 0x7FFF + ((v.u >> 16) & 1)) >> 16;   // RNE
    return (ushort)r;
}
__device__ __forceinline__ float bf2f(ushort u) {
    union { unsigned u; float f; } v; v.u = ((unsigned)u) << 16;
    return v.f;
}

// ---------------------------------------------------------------------------
__global__ __launch_bounds__(256) void init_kernel(int* __restrict__ cnt,
                                                   int* __restrict__ need,
                                                   int* __restrict__ inv,
                                                   int* __restrict__ counter) {
    int t = blockIdx.x * 256 + threadIdx.x;
    if (t < NTOK) { cnt[t] = 0; need[t] = 0; inv[t] = -1; }
    if (t == 0) *counter = 0;
}

// ---------------------------------------------------------------------------
__global__ __launch_bounds__(256) void convw_kernel(const float* __restrict__ W,
                                                    ushort* __restrict__ Wb) {
    int i = blockIdx.x * 256 + threadIdx.x;   // float4 index
    float4 v = ((const float4*)W)[i];
    ushort4 o;
    o.x = f2bf(v.x); o.y = f2bf(v.y); o.z = f2bf(v.z); o.w = f2bf(v.w);
    ((ushort4*)Wb)[i] = o;
}

// ---------------------------------------------------------------------------
__global__ __launch_bounds__(256) void prep_kernel(const int* __restrict__ red,
                                                   const int* __restrict__ sav,
                                                   int* __restrict__ cnt,
                                                   int* __restrict__ need) {
    int j = blockIdx.x * 256 + threadIdx.x;
    if (j >= NRED) return;
    atomicAdd(&cnt[red[j]], 1);
    int s = sav[j];
    if (s > 0) need[s - 1] = 1;
}

// ---------------------------------------------------------------------------
__global__ __launch_bounds__(256) void compact_kernel(const int* __restrict__ cnt,
                                                      const int* __restrict__ need,
                                                      int* __restrict__ inv,
                                                      int* __restrict__ list,
                                                      int* __restrict__ counter) {
    int t = blockIdx.x * 256 + threadIdx.x;
    if (t >= NTOK) return;
    if (need[t] && cnt[t] > 0) {
        int pos = atomicAdd(counter, 1);
        inv[t] = pos;
        list[pos] = t;
    }
}

// ---------------------------------------------------------------------------
// bf16 MFMA GEMM: Tb[m, n] = bf16( sum_k X[list[m], k] * W[n, k] )
// BM=64, BN=128, BK=32; 256 threads = 4 waves; wave tile 32x64 (2x4 frags of
// 16x16x32). A reg-staged (fp32->bf16 convert) with swizzled ds_write_b128;
// B staged via global_load_lds(16) with pre-swizzled SOURCE address so the
// linear LDS dest lands swizzled (rule #21). Swizzle: 16B slot ^= (row>>1)&3
// -> ds_read_b128 2-way bank aliasing (free, m136).
// ---------------------------------------------------------------------------
#define BM 64
#define BN 128
#define BK 32

__global__ __launch_bounds__(256) void gemm_kernel(const float* __restrict__ X,
                                                   const ushort* __restrict__ Wb,
                                                   const int* __restrict__ list,
                                                   const int* __restrict__ counter,
                                                   ushort* __restrict__ Tb) {
    const int M = *counter;
    const int m0 = blockIdx.y * BM;
    if (m0 >= M) return;
    const int n0 = blockIdx.x * BN;

    __shared__ ushort As[BM * BK];   // 4 KB (swizzled)
    __shared__ ushort Bs[BN * BK];   // 8 KB (swizzled)

    const int tid  = threadIdx.x;
    const int lane = tid & 63;
    const int wid  = tid >> 6;
    const int wr   = wid >> 1;       // 0..1  (32-row band)
    const int wc   = wid & 1;        // 0..1  (64-col band)
    const int kgrp = lane >> 4;      // 0..3
    const int r16  = lane & 15;

    // ---- A staging geometry: thread covers (row = tid>>2, slot = tid&3) ----
    const int arow  = tid >> 2;      // 0..63
    const int aslot = tid & 3;       // 8 fp32 each
    int am = m0 + arow;
    int src = list[am < M ? am : M - 1];
    const float* aptr = X + (size_t)src * DM + aslot * 8;
    const int awidx = arow * BK + ((aslot ^ ((arow >> 1) & 3)) * 8); // ushort idx

    // ---- B staging: global_load_lds, source pre-swizzled ----
    const int brow0 = n0 + (tid >> 2);                    // issue-0 global row
    const int bxs   = (tid & 3) ^ ((brow0 >> 1) & 3);     // swizzled k-slot
    const ushort* bptr = Wb + (size_t)brow0 * DM + bxs * 8;
    char* BsBase = (char*)Bs + wid * 1024;                // wave-uniform dest

    // ---- fragment read offsets (swizzled) ----
    int aoff[2], boff[4];
#pragma unroll
    for (int fm = 0; fm < 2; ++fm) {
        int row = wr * 32 + fm * 16 + r16;
        aoff[fm] = row * BK + ((kgrp ^ ((row >> 1) & 3)) * 8);
    }
#pragma unroll
    for (int fn = 0; fn < 4; ++fn) {
        int row = wc * 64 + fn * 16 + r16;
        boff[fn] = row * BK + ((kgrp ^ ((row >> 1) & 3)) * 8);
    }

    f32x4 acc[2][4] = {};

    for (int k0 = 0; k0 < DM; k0 += BK) {
        float4 a0 = *(const float4*)(aptr + k0);
        float4 a1 = *(const float4*)(aptr + k0 + 4);
        __syncthreads();   // previous iteration's ds_reads complete
        __builtin_amdgcn_global_load_lds(
            (const __attribute__((address_space(1))) unsigned*)(bptr + k0),
            (__attribute__((address_space(3))) unsigned*)(BsBase), 16, 0, 0);
        __builtin_amdgcn_global_load_lds(
            (const __attribute__((address_space(1))) unsigned*)(bptr + k0 + 64 * DM),
            (__attribute__((address_space(3))) unsigned*)(BsBase + 4096), 16, 0, 0);
        bf16x8 av;
        av[0] = (short)f2bf(a0.x); av[1] = (short)f2bf(a0.y);
        av[2] = (short)f2bf(a0.z); av[3] = (short)f2bf(a0.w);
        av[4] = (short)f2bf(a1.x); av[5] = (short)f2bf(a1.y);
        av[6] = (short)f2bf(a1.z); av[7] = (short)f2bf(a1.w);
        *(bf16x8*)(As + awidx) = av;
        __syncthreads();   // drains vmcnt (gload_lds) + lgkm (ds_write)

        bf16x8 af0 = *(const bf16x8*)(As + aoff[0]);
        bf16x8 af1 = *(const bf16x8*)(As + aoff[1]);
        bf16x8 bf0 = *(const bf16x8*)(Bs + boff[0]);
        bf16x8 bf1 = *(const bf16x8*)(Bs + boff[1]);
        bf16x8 bf2 = *(const bf16x8*)(Bs + boff[2]);
        bf16x8 bf3 = *(const bf16x8*)(Bs + boff[3]);
        acc[0][0] = __builtin_amdgcn_mfma_f32_16x16x32_bf16(af0, bf0, acc[0][0], 0, 0, 0);
        acc[0][1] = __builtin_amdgcn_mfma_f32_16x16x32_bf16(af0, bf1, acc[0][1], 0, 0, 0);
        acc[0][2] = __builtin_amdgcn_mfma_f32_16x16x32_bf16(af0, bf2, acc[0][2], 0, 0, 0);
        acc[0][3] = __builtin_amdgcn_mfma_f32_16x16x32_bf16(af0, bf3, acc[0][3], 0, 0, 0);
        acc[1][0] = __builtin_amdgcn_mfma_f32_16x16x32_bf16(af1, bf0, acc[1][0], 0, 0, 0);
        acc[1][1] = __builtin_amdgcn_mfma_f32_16x16x32_bf16(af1, bf1, acc[1][1], 0, 0, 0);
        acc[1][2] = __builtin_amdgcn_mfma_f32_16x16x32_bf16(af1, bf2, acc[1][2], 0, 0, 0);
        acc[1][3] = __builtin_amdgcn_mfma_f32_16x16x32_bf16(af1, bf3, acc[1][3], 0, 0, 0);
    }

    // C/D layout: col = lane&15, row = (lane>>4)*4 + reg  [m89]
#pragma unroll
    for (int fm = 0; fm < 2; ++fm) {
        int mbase = m0 + wr * 32 + fm * 16 + kgrp * 4;
#pragma unroll
        for (int fn = 0; fn < 4; ++fn) {
            int n = n0 + wc * 64 + fn * 16 + r16;
#pragma unroll
            for (int r = 0; r < 4; ++r) {
                int m = mbase + r;
                if (m < M) Tb[(size_t)m * DM + n] = f2bf(acc[fm][fn][r]);
            }
        }
    }
}

// ---------------------------------------------------------------------------
// epilogue: out[r] = x[s] + cnt[s-1] * Tb[inv[s-1]]
// ---------------------------------------------------------------------------
__global__ __launch_bounds__(256) void out_kernel(const float* __restrict__ X,
                                                  const ushort* __restrict__ Tb,
                                                  const int* __restrict__ sav,
                                                  const int* __restrict__ cnt,
                                                  const int* __restrict__ inv,
                                                  float* __restrict__ out) {
    int r = blockIdx.x;
    int d = threadIdx.x;                 // float4 lane, 0..255
    int s = sav[r];
    const float4* xr = (const float4*)(X + (size_t)s * DM);
    float4 v = xr[d];
    if (s > 0) {
        int t = s - 1;
        int c = cnt[t];
        if (c > 0) {
            float fc = (float)c;
            const ushort4* tr = (const ushort4*)(Tb + (size_t)inv[t] * DM);
            ushort4 w = tr[d];
            v.x += fc * bf2f(w.x); v.y += fc * bf2f(w.y);
            v.z += fc * bf2f(w.z); v.w += fc * bf2f(w.w);
        }
    }
    ((float4*)out)[(size_t)r * (DM / 4) + d] = v;
}

// ---------------------------------------------------------------------------
extern "C" void kernel_launch(void* const* d_in, const int* in_sizes, int n_in,
                              void* d_out, int out_size, void* d_ws, size_t ws_size,
                              hipStream_t stream) {
    const float* X   = (const float*)d_in[0];
    const float* W   = (const float*)d_in[1];
    const int*   sav = (const int*)d_in[2];   // ids_to_save
    const int*   red = (const int*)d_in[3];   // ids_to_reduce
    float* out = (float*)d_out;

    char* ws = (char*)d_ws;
    int* counter = (int*)ws;                  // 64 ints
    int* cnt  = counter + 64;                 // 32768
    int* need = cnt + NTOK;                   // 32768
    int* inv  = need + NTOK;                  // 32768
    int* list = inv + NTOK;                   // 16384  (ends < 512 KB)
    ushort* Wb = (ushort*)(ws + (1 << 19));   // 2 MB bf16 W
    ushort* Tb = (ushort*)(ws + (4 << 20));   // 32 MB bf16 T (<= 36 MB total)

    init_kernel<<<NTOK / 256, 256, 0, stream>>>(cnt, need, inv, counter);
    convw_kernel<<<DM * DM / 4 / 256, 256, 0, stream>>>(W, Wb);
    prep_kernel<<<NRED / 256, 256, 0, stream>>>(red, sav, cnt, need);
    compact_kernel<<<NTOK / 256, 256, 0, stream>>>(cnt, need, inv, list, counter);

    dim3 ggrid(DM / BN, NRED / BM);           // 8 x 256, early-exit on m0 >= M
    gemm_kernel<<<ggrid, 256, 0, stream>>>(X, Wb, list, counter, Tb);

    out_kernel<<<NSAVE, 256, 0, stream>>>(X, Tb, sav, cnt, inv, out);
}